// Round 1
// baseline (238.284 us; speedup 1.0000x reference)
//
#include <hip/hip_runtime.h>
#include <hip/hip_bf16.h>

#define NROWS 8192
#define DIM 256

typedef __attribute__((ext_vector_type(8))) short short8;
typedef __attribute__((ext_vector_type(4))) float f32x4;

__device__ __forceinline__ ushort f2bf(float f) {
  unsigned u = __float_as_uint(f);
  u += 0x7fffu + ((u >> 16) & 1u);   // round-to-nearest-even
  return (ushort)(u >> 16);
}
__device__ __forceinline__ float bf2f(ushort b) {
  return __uint_as_float(((unsigned)b) << 16);
}

// ---- prep: f32 -> bf16 copy + row sum-of-squares (of the bf16-rounded values)
__global__ __launch_bounds__(256) void prep_kernel(
    const float* __restrict__ S, const float* __restrict__ T,
    ushort* __restrict__ Sb, ushort* __restrict__ Tb,
    float* __restrict__ x2s, float* __restrict__ x2t) {
  const int w = threadIdx.x >> 6, l = threadIdx.x & 63;
  const int r = blockIdx.x * 4 + w;
  const float* src;
  ushort* dst;
  float* sq;
  int row;
  if (r < NROWS) { src = S; dst = Sb; sq = x2s; row = r; }
  else           { src = T; dst = Tb; sq = x2t; row = r - NROWS; }

  const float4 v = *(const float4*)(src + (size_t)row * DIM + l * 4);
  float vf[4] = {v.x, v.y, v.z, v.w};
  ushort b[4];
  float s = 0.f;
#pragma unroll
  for (int i = 0; i < 4; ++i) {
    b[i] = f2bf(vf[i]);
    float f = bf2f(b[i]);
    s += f * f;
  }
  ushort4 bv = make_ushort4(b[0], b[1], b[2], b[3]);
  *(ushort4*)(dst + (size_t)row * DIM + l * 4) = bv;
#pragma unroll
  for (int off = 32; off > 0; off >>= 1) s += __shfl_xor(s, off);
  if (l == 0) sq[row] = s;
}

__device__ __forceinline__ void gload_lds16(const void* g, void* lds) {
  __builtin_amdgcn_global_load_lds(
      (const __attribute__((address_space(1))) unsigned int*)g,
      (__attribute__((address_space(3))) unsigned int*)lds, 16, 0, 0);
}

// ---- fused GEMM + exp + reduce. Grid: 3 * 64 * 64 blocks (SS, TT, ST tiles).
__global__ __launch_bounds__(256) void mmd_gemm(
    const ushort* __restrict__ Sb, const ushort* __restrict__ Tb,
    const float* __restrict__ x2s, const float* __restrict__ x2t,
    float* __restrict__ accums) {
  __shared__ __align__(16) ushort lA[128 * 32];
  __shared__ __align__(16) ushort lB[128 * 32];
  __shared__ float lAx2[128];
  __shared__ float lBx2[128];
  __shared__ float wsum[4];

  const int tid = threadIdx.x;
  const int l = tid & 63;
  const int w = tid >> 6;
  const int wr = w >> 1, wc = w & 1;   // 2x2 waves over the 128x128 tile

  const int bid = blockIdx.x;
  const int mat = bid >> 12;           // 4096 tiles per matrix
  const int t = bid & 4095;
  const int tr = t >> 6, tc = t & 63;

  const ushort* Ap;
  const ushort* Bp;
  const float* a2;
  const float* b2;
  int ai;
  if (mat == 0)      { Ap = Sb; Bp = Sb; a2 = x2s; b2 = x2s; ai = 0; }
  else if (mat == 1) { Ap = Tb; Bp = Tb; a2 = x2t; b2 = x2t; ai = 1; }
  else               { Ap = Sb; Bp = Tb; a2 = x2s; b2 = x2t; ai = 2; }

  const int aRow0 = tr * 128, bRow0 = tc * 128;

  if (tid < 128) lAx2[tid] = a2[aRow0 + tid];
  else           lBx2[tid - 128] = b2[bRow0 + tid - 128];

  f32x4 acc[4][4];
  const f32x4 zero = {0.f, 0.f, 0.f, 0.f};
#pragma unroll
  for (int m = 0; m < 4; ++m)
#pragma unroll
    for (int n = 0; n < 4; ++n) acc[m][n] = zero;

#pragma unroll
  for (int ks = 0; ks < 8; ++ks) {
    const int k0 = ks * 32;
    // stage A and B tiles: [128 rows][32 k] bf16, linear LDS, 16B/lane chunks
#pragma unroll
    for (int g = 0; g < 2; ++g) {
      const int c = (g * 4 + w) * 64 + l;  // 16B-chunk index 0..511
      const int row = c >> 2;
      const int kc = c & 3;
      gload_lds16(Ap + (size_t)(aRow0 + row) * DIM + k0 + kc * 8, &lA[c * 8]);
      gload_lds16(Bp + (size_t)(bRow0 + row) * DIM + k0 + kc * 8, &lB[c * 8]);
    }
    __syncthreads();   // drains vmcnt before barrier (compiler-inserted)

    short8 af[4], bfr[4];
#pragma unroll
    for (int m = 0; m < 4; ++m)
      af[m] = *(const short8*)&lA[(wr * 64 + m * 16 + (l & 15)) * 32 + (l >> 4) * 8];
#pragma unroll
    for (int n = 0; n < 4; ++n)
      bfr[n] = *(const short8*)&lB[(wc * 64 + n * 16 + (l & 15)) * 32 + (l >> 4) * 8];
#pragma unroll
    for (int m = 0; m < 4; ++m)
#pragma unroll
      for (int n = 0; n < 4; ++n)
        acc[m][n] = __builtin_amdgcn_mfma_f32_16x16x32_bf16(af[m], bfr[n], acc[m][n], 0, 0, 0);
    __syncthreads();
  }

  // ---- fused epilogue: d2 = x2_i + x2_j - 2*dot ; sum exp(-0.5*d2)
  float cb[4];
#pragma unroll
  for (int n = 0; n < 4; ++n) cb[n] = lBx2[wc * 64 + n * 16 + (l & 15)];
  float local = 0.f;
#pragma unroll
  for (int m = 0; m < 4; ++m) {
#pragma unroll
    for (int j = 0; j < 4; ++j) {
      const float ra = lAx2[wr * 64 + m * 16 + ((l >> 4) * 4 + j)];
#pragma unroll
      for (int n = 0; n < 4; ++n) {
        float d2 = fmaf(-2.f, acc[m][n][j], ra + cb[n]);
        d2 = fmaxf(d2, 0.f);
        local += __expf(-0.5f * d2);
      }
    }
  }
#pragma unroll
  for (int off = 32; off > 0; off >>= 1) local += __shfl_xor(local, off);
  if (l == 0) wsum[w] = local;
  __syncthreads();
  if (tid == 0) atomicAdd(&accums[ai], wsum[0] + wsum[1] + wsum[2] + wsum[3]);
}

__global__ void finalize_kernel(const float* __restrict__ accums, float* __restrict__ out) {
  out[0] = (accums[0] + accums[1] - 2.f * accums[2]) * (1.f / ((float)NROWS * (float)NROWS));
}

extern "C" void kernel_launch(void* const* d_in, const int* in_sizes, int n_in,
                              void* d_out, int out_size, void* d_ws, size_t ws_size,
                              hipStream_t stream) {
  const float* S = (const float*)d_in[0];
  const float* T = (const float*)d_in[1];
  float* out = (float*)d_out;

  ushort* Sb = (ushort*)d_ws;                      // 4 MB
  ushort* Tb = Sb + (size_t)NROWS * DIM;           // 4 MB
  float* x2s = (float*)(Tb + (size_t)NROWS * DIM); // 32 KB
  float* x2t = x2s + NROWS;                        // 32 KB
  float* accums = x2t + NROWS;                     // 3 floats (ws poisoned -> zero them)

  hipMemsetAsync(accums, 0, 4 * sizeof(float), stream);
  prep_kernel<<<(2 * NROWS) / 4, 256, 0, stream>>>(S, T, Sb, Tb, x2s, x2t);
  mmd_gemm<<<3 * 64 * 64, 256, 0, stream>>>(Sb, Tb, x2s, x2t, accums);
  finalize_kernel<<<1, 1, 0, stream>>>(accums, out);
}